// Round 13
// baseline (71.612 us; speedup 1.0000x reference)
//
#include <hip/hip_runtime.h>

#define NPART 128
#define NDIM  128
#define BATCH 4096
#define NBLK  1024                    // (particle:128) x (rowhalf:2) x (quarter:4)
#define NXCD  8
#define YCH   12                      // y rows per LDS chunk

// ---------------------------------------------------------------------------
// Single fused kernel: 1024 blocks x 256 threads.
// Block = (p, h, q): particle p, output rows [h*64, h*64+64), quarter q of
// p's bucket. All 8 siblings of p compute the identical selection scan
// (deterministic, rank = sid order) -> exact partition, no atomics, no ws.
//   1. randind int4 loads first (not blocked by sigma vmcnt),
//   2. softmax scalars (wave 0) -> LDS,
//   3. wave-shfl scan + 1 barrier; rank loop also emits wout/indout (h==0),
//   4. sigma half-tile (32 KB) -> XOR-swizzled LDS (transient regs),
//   5. row -> 32 float4 regs; per 12-sample chunk: y rows -> LDS (coalesced),
//      inner loop: broadcast ds_reads + register fmacs, 4-way sample split.
// ---------------------------------------------------------------------------
__global__ __launch_bounds__(256, 3)
void mix_kernel(const float* __restrict__ gaussian,  // [BATCH, NDIM]
                const float* __restrict__ logp,      // [NPART]
                const float* __restrict__ pos,       // [NPART, NDIM]
                const float* __restrict__ sigma,     // [NPART, NDIM, NDIM]
                const int*   __restrict__ randind,   // [BATCH]
                float* __restrict__ out,             // [BATCH, NDIM]
                float* __restrict__ wout,            // [BATCH]
                float* __restrict__ indout) {        // [BATCH]
    const int g  = blockIdx.x;
    // XCD-chunked bijective swizzle (1024 % 8 == 0): all 8 siblings of a
    // particle land on one XCD -> sigma_p + y rows HBM-fetched once, L2-reused.
    const int sg = (g % NXCD) * (NBLK / NXCD) + g / NXCD;
    const int p  = sg >> 3;            // particle
    const int h  = (sg >> 2) & 1;      // row half
    const int q  = sg & 3;             // quarter of bucket
    const int t  = threadIdx.x;
    const int row  = t & 63;           // row within half
    const int quad = t >> 6;           // sample-mod-4 lane group (= wave id)
    const int lane = t & 63;

    __shared__ float4 smat[64 * 32];             // 32 KB swizzled sigma half
    __shared__ float  ylds[YCH][NDIM];           // 6 KB y chunk
    __shared__ int    slist[96];                 // sids of my quarter
    __shared__ int    wtot[4];
    __shared__ float  smx[2];                    // softmax m, S

    // ---- 1. selection loads first: thread t owns samples [16t, 16t+16) ----
    const int4* rnd4 = reinterpret_cast<const int4*>(randind);
    int mk[16];
    {
        int4 a = rnd4[t * 4 + 0], b = rnd4[t * 4 + 1],
             c = rnd4[t * 4 + 2], d = rnd4[t * 4 + 3];
        mk[0]=a.x;  mk[1]=a.y;  mk[2]=a.z;  mk[3]=a.w;
        mk[4]=b.x;  mk[5]=b.y;  mk[6]=b.z;  mk[7]=b.w;
        mk[8]=c.x;  mk[9]=c.y;  mk[10]=c.z; mk[11]=c.w;
        mk[12]=d.x; mk[13]=d.y; mk[14]=d.z; mk[15]=d.w;
    }

    // ---- 2. softmax scalars by wave 0 ----
    if (t < 64) {
        float a = logp[t], b = logp[t + 64];
        float m = fmaxf(a, b);
        #pragma unroll
        for (int o = 32; o > 0; o >>= 1) m = fmaxf(m, __shfl_xor(m, o));
        float ea = expf(a - m), eb = expf(b - m);
        float s = ea + eb;
        #pragma unroll
        for (int o = 32; o > 0; o >>= 1) s += __shfl_xor(s, o);
        if (t == 0) { smx[0] = m; smx[1] = s; }
    }

    // ---- 3. wave-shfl scan + rank loop (emits wout/indout on h==0) ----
    int cnt = 0;
    #pragma unroll
    for (int k = 0; k < 16; ++k) cnt += (mk[k] == p) ? 1 : 0;
    int v = cnt;                                   // inclusive wave scan
    #pragma unroll
    for (int o = 1; o < 64; o <<= 1) {
        int u = __shfl_up(v, o);
        if (lane >= o) v += u;
    }
    if (lane == 63) wtot[quad] = v;
    __syncthreads();                               // barrier #1
    int woff = 0;
    #pragma unroll
    for (int w = 0; w < 4; ++w) woff += (w < quad) ? wtot[w] : 0;
    const int base = woff + v - cnt;               // block-wide exclusive
    const int n    = wtot[0] + wtot[1] + wtot[2] + wtot[3];
    const int lo   = (n * q) / 4;
    const int hi   = (n * (q + 1)) / 4;
    const int nq   = hi - lo;
    const float pw = expf(logp[p] - smx[0]) / smx[1];
    {
        int r = base;
        #pragma unroll
        for (int k = 0; k < 16; ++k) {
            if (mk[k] == p) {
                if (r >= lo && r < hi && (r - lo) < 96) {
                    slist[r - lo] = t * 16 + k;
                    if (h == 0) {                  // once globally per sample
                        wout[t * 16 + k]   = pw;
                        indout[t * 16 + k] = (float)p;
                    }
                }
                ++r;
            }
        }
    }
    if (nq == 0) return;               // uniform across block, safe

    // ---- 4. sigma half-tile -> LDS (XOR-swizzled), transient regs ----
    const float4* src = reinterpret_cast<const float4*>(sigma)
                        + (size_t)p * 4096 + h * 2048;
    #pragma unroll
    for (int w = 0; w < 8; ++w) {
        int idx = w * 256 + t;                   // 0..2047 linear float4
        int r = idx >> 5, u = idx & 31;
        smat[r * 32 + (u ^ (r & 7))] = src[idx];
    }
    __syncthreads();                               // barrier #2

    // ---- 5. row -> 32 float4 regs; chunked y-LDS + fmac loop ----
    float4 sr[32];
    #pragma unroll
    for (int u = 0; u < 32; ++u)
        sr[u] = smat[row * 32 + (u ^ (row & 7))];

    const float posv = pos[p * NDIM + h * 64 + row];
    const float4* g4 = reinterpret_cast<const float4*>(gaussian);

    for (int c0 = 0; c0 < nq; c0 += YCH) {
        const int m = min(YCH, nq - c0);
        if (c0 > 0) __syncthreads();               // prev chunk readers done
        #pragma unroll
        for (int it = 0; it < 2; ++it) {           // stage <=12 y rows
            int idx = it * 256 + t;                // 0..511; need < m*32
            int yr = idx >> 5, u = idx & 31;
            if (yr < m) {
                int sid = slist[c0 + yr];
                reinterpret_cast<float4*>(ylds[yr])[u] = g4[sid * 32 + u];
            }
        }
        __syncthreads();                           // y chunk ready

        for (int sl = quad; sl < m; sl += 4) {
            const int sid = __builtin_amdgcn_readfirstlane(slist[c0 + sl]);
            const float4* y4 = reinterpret_cast<const float4*>(ylds[sl]);
            float a0 = 0.f, a1 = 0.f, a2 = 0.f, a3 = 0.f;
            #pragma unroll
            for (int u = 0; u < 32; ++u) {
                float4 yv = y4[u];                 // same-addr broadcast
                float4 sv = sr[u];
                a0 += sv.x * yv.x;  a1 += sv.y * yv.y;
                a2 += sv.z * yv.z;  a3 += sv.w * yv.w;
            }
            out[sid * NDIM + h * 64 + row] = posv + ((a0 + a1) + (a2 + a3));
        }
    }
}

extern "C" void kernel_launch(void* const* d_in, const int* in_sizes, int n_in,
                              void* d_out, int out_size, void* d_ws, size_t ws_size,
                              hipStream_t stream) {
    const float* gaussian = (const float*)d_in[0];   // [4096,128]
    const float* logp     = (const float*)d_in[1];   // [128,1]
    const float* pos      = (const float*)d_in[2];   // [128,128]
    const float* sigma    = (const float*)d_in[3];   // [128,128,128]
    const int*   randind  = (const int*)d_in[4];     // [4096]

    float* out    = (float*)d_out;            // [4096*128]
    float* wout   = out + BATCH * NDIM;       // [4096]
    float* indout = wout + BATCH;             // [4096]

    mix_kernel<<<NBLK, 256, 0, stream>>>(gaussian, logp, pos, sigma, randind,
                                         out, wout, indout);
}

// Round 14
// 19.183 us; speedup vs baseline: 3.7330x; 3.7330x over previous
//
#include <hip/hip_runtime.h>

#define NPART 128
#define NDIM  128
#define BATCH 4096
#define NBLK  1024                    // (particle:128) x (rowhalf:2) x (quarter:4)
#define NXCD  8
#define YCH   12                      // y rows per LDS chunk

// ---------------------------------------------------------------------------
// Single fused kernel: 1024 blocks x 256 threads.
// Block = (p, h, q): particle p, output rows [h*64, h*64+64), quarter q of
// p's bucket. All 8 siblings of p compute the identical selection scan
// (deterministic, rank = sid order) -> exact partition, no atomics, no ws.
// NOTE (R13 post-mortem): NO min-waves arg in launch_bounds — capping VGPR
// at 84 spilled sr[32] (128 regs) to scratch = 114 MB HBM round-trip.
// ---------------------------------------------------------------------------
__global__ __launch_bounds__(256)
void mix_kernel(const float* __restrict__ gaussian,  // [BATCH, NDIM]
                const float* __restrict__ logp,      // [NPART]
                const float* __restrict__ pos,       // [NPART, NDIM]
                const float* __restrict__ sigma,     // [NPART, NDIM, NDIM]
                const int*   __restrict__ randind,   // [BATCH]
                float* __restrict__ out,             // [BATCH, NDIM]
                float* __restrict__ wout,            // [BATCH]
                float* __restrict__ indout) {        // [BATCH]
    const int g  = blockIdx.x;
    // XCD-chunked bijective swizzle (1024 % 8 == 0): all 8 siblings of a
    // particle land on one XCD -> sigma_p + y rows HBM-fetched once, L2-reused.
    const int sg = (g % NXCD) * (NBLK / NXCD) + g / NXCD;
    const int p  = sg >> 3;            // particle
    const int h  = (sg >> 2) & 1;      // row half
    const int q  = sg & 3;             // quarter of bucket
    const int t  = threadIdx.x;
    const int row  = t & 63;           // row within half
    const int quad = t >> 6;           // sample-mod-4 lane group (= wave id)
    const int lane = t & 63;

    __shared__ float4 smat[64 * 32];             // 32 KB swizzled sigma half
    __shared__ float  ylds[YCH][NDIM];           // 6 KB y chunk
    __shared__ int    slist[96];                 // sids of my quarter
    __shared__ int    wtot[4];
    __shared__ float  smx[2];                    // softmax m, S

    // ---- 1. selection loads first: thread t owns samples [16t, 16t+16) ----
    const int4* rnd4 = reinterpret_cast<const int4*>(randind);
    int mk[16];
    {
        int4 a = rnd4[t * 4 + 0], b = rnd4[t * 4 + 1],
             c = rnd4[t * 4 + 2], d = rnd4[t * 4 + 3];
        mk[0]=a.x;  mk[1]=a.y;  mk[2]=a.z;  mk[3]=a.w;
        mk[4]=b.x;  mk[5]=b.y;  mk[6]=b.z;  mk[7]=b.w;
        mk[8]=c.x;  mk[9]=c.y;  mk[10]=c.z; mk[11]=c.w;
        mk[12]=d.x; mk[13]=d.y; mk[14]=d.z; mk[15]=d.w;
    }

    // ---- 2. softmax scalars by wave 0 ----
    if (t < 64) {
        float a = logp[t], b = logp[t + 64];
        float m = fmaxf(a, b);
        #pragma unroll
        for (int o = 32; o > 0; o >>= 1) m = fmaxf(m, __shfl_xor(m, o));
        float ea = expf(a - m), eb = expf(b - m);
        float s = ea + eb;
        #pragma unroll
        for (int o = 32; o > 0; o >>= 1) s += __shfl_xor(s, o);
        if (t == 0) { smx[0] = m; smx[1] = s; }
    }

    // ---- 3. wave-shfl scan + rank loop (emits wout/indout on h==0) ----
    int cnt = 0;
    #pragma unroll
    for (int k = 0; k < 16; ++k) cnt += (mk[k] == p) ? 1 : 0;
    int v = cnt;                                   // inclusive wave scan
    #pragma unroll
    for (int o = 1; o < 64; o <<= 1) {
        int u = __shfl_up(v, o);
        if (lane >= o) v += u;
    }
    if (lane == 63) wtot[quad] = v;
    __syncthreads();                               // barrier #1
    int woff = 0;
    #pragma unroll
    for (int w = 0; w < 4; ++w) woff += (w < quad) ? wtot[w] : 0;
    const int base = woff + v - cnt;               // block-wide exclusive
    const int n    = wtot[0] + wtot[1] + wtot[2] + wtot[3];
    const int lo   = (n * q) / 4;
    const int hi   = (n * (q + 1)) / 4;
    const int nq   = hi - lo;
    const float pw = expf(logp[p] - smx[0]) / smx[1];
    {
        int r = base;
        #pragma unroll
        for (int k = 0; k < 16; ++k) {
            if (mk[k] == p) {
                if (r >= lo && r < hi && (r - lo) < 96) {
                    slist[r - lo] = t * 16 + k;
                    if (h == 0) {                  // once globally per sample
                        wout[t * 16 + k]   = pw;
                        indout[t * 16 + k] = (float)p;
                    }
                }
                ++r;
            }
        }
    }
    if (nq == 0) return;               // uniform across block, safe

    // ---- 4. sigma half-tile -> LDS (XOR-swizzled), transient regs ----
    const float4* src = reinterpret_cast<const float4*>(sigma)
                        + (size_t)p * 4096 + h * 2048;
    #pragma unroll
    for (int w = 0; w < 8; ++w) {
        int idx = w * 256 + t;                   // 0..2047 linear float4
        int r = idx >> 5, u = idx & 31;
        smat[r * 32 + (u ^ (r & 7))] = src[idx];
    }
    __syncthreads();                               // barrier #2

    // ---- 5. row -> 32 float4 regs; chunked y-LDS + fmac loop ----
    float4 sr[32];
    #pragma unroll
    for (int u = 0; u < 32; ++u)
        sr[u] = smat[row * 32 + (u ^ (row & 7))];

    const float posv = pos[p * NDIM + h * 64 + row];
    const float4* g4 = reinterpret_cast<const float4*>(gaussian);

    for (int c0 = 0; c0 < nq; c0 += YCH) {
        const int m = min(YCH, nq - c0);
        if (c0 > 0) __syncthreads();               // prev chunk readers done
        #pragma unroll
        for (int it = 0; it < 2; ++it) {           // stage <=12 y rows
            int idx = it * 256 + t;                // 0..511; need < m*32
            int yr = idx >> 5, u = idx & 31;
            if (yr < m) {
                int sid = slist[c0 + yr];
                reinterpret_cast<float4*>(ylds[yr])[u] = g4[sid * 32 + u];
            }
        }
        __syncthreads();                           // y chunk ready

        for (int sl = quad; sl < m; sl += 4) {
            const int sid = __builtin_amdgcn_readfirstlane(slist[c0 + sl]);
            const float4* y4 = reinterpret_cast<const float4*>(ylds[sl]);
            float a0 = 0.f, a1 = 0.f, a2 = 0.f, a3 = 0.f;
            #pragma unroll
            for (int u = 0; u < 32; ++u) {
                float4 yv = y4[u];                 // same-addr broadcast
                float4 sv = sr[u];
                a0 += sv.x * yv.x;  a1 += sv.y * yv.y;
                a2 += sv.z * yv.z;  a3 += sv.w * yv.w;
            }
            out[sid * NDIM + h * 64 + row] = posv + ((a0 + a1) + (a2 + a3));
        }
    }
}

extern "C" void kernel_launch(void* const* d_in, const int* in_sizes, int n_in,
                              void* d_out, int out_size, void* d_ws, size_t ws_size,
                              hipStream_t stream) {
    const float* gaussian = (const float*)d_in[0];   // [4096,128]
    const float* logp     = (const float*)d_in[1];   // [128,1]
    const float* pos      = (const float*)d_in[2];   // [128,128]
    const float* sigma    = (const float*)d_in[3];   // [128,128,128]
    const int*   randind  = (const int*)d_in[4];     // [4096]

    float* out    = (float*)d_out;            // [4096*128]
    float* wout   = out + BATCH * NDIM;       // [4096]
    float* indout = wout + BATCH;             // [4096]

    mix_kernel<<<NBLK, 256, 0, stream>>>(gaussian, logp, pos, sigma, randind,
                                         out, wout, indout);
}

// Round 15
// 15.945 us; speedup vs baseline: 4.4912x; 1.2031x over previous
//
#include <hip/hip_runtime.h>

#define NPART 128
#define NDIM  128
#define BATCH 4096
#define BPP   4                       // blocks per particle
#define NBLK  (NPART * BPP)           // 512 blocks
#define NXCD  8

typedef __attribute__((address_space(1))) const unsigned int guint;
typedef __attribute__((address_space(3))) unsigned int luint;

// ---------------------------------------------------------------------------
// Single fused kernel: 512 blocks x 256 threads. Block = (particle p, qtr q).
// R12 structure (best: 16.0us) with ONE change: sigma staging now uses
// global_load_lds with pre-swizzled per-lane SOURCE addresses and a linear
// wave-uniform LDS dest (G21/m173) -- same final swizzled layout, no VGPR
// round-trip, no ds_write issue cost, loads drain once at barrier #2.
// ---------------------------------------------------------------------------
__global__ __launch_bounds__(256)
void mix_kernel(const float* __restrict__ gaussian,  // [BATCH, NDIM]
                const float* __restrict__ logp,      // [NPART]
                const float* __restrict__ pos,       // [NPART, NDIM]
                const float* __restrict__ sigma,     // [NPART, NDIM, NDIM]
                const int*   __restrict__ randind,   // [BATCH]
                float* __restrict__ out,             // [BATCH, NDIM]
                float* __restrict__ wout,            // [BATCH]
                float* __restrict__ indout) {        // [BATCH]
    const int g  = blockIdx.x;
    // XCD-chunked bijective swizzle (512 % 8 == 0): a particle's 4 sibling
    // blocks land on the same XCD -> sigma_p HBM-fetched once, L2-served 3x.
    const int sg = (g % NXCD) * (NBLK / NXCD) + g / NXCD;
    const int p  = sg >> 2;            // particle
    const int q  = sg & 3;             // quarter of bucket
    const int t  = threadIdx.x;
    const int i  = t & 127;            // output row
    const int hf = t >> 7;             // sample-parity half
    const int lane = t & 63, wid = t >> 6;

    __shared__ float4 smat[NDIM * 32];           // 64 KB swizzled sigma_p
    __shared__ int    wtot[4];
    __shared__ int    slist[160];                // sids of my quarter
    __shared__ float  smx[2];                    // softmax m, S

    // ---- 1. selection loads first: thread t owns samples [16t, 16t+16) ----
    const int4* rnd4 = reinterpret_cast<const int4*>(randind);
    int mk[16];
    {
        int4 a = rnd4[t * 4 + 0], b = rnd4[t * 4 + 1],
             c = rnd4[t * 4 + 2], d = rnd4[t * 4 + 3];
        mk[0]=a.x;  mk[1]=a.y;  mk[2]=a.z;  mk[3]=a.w;
        mk[4]=b.x;  mk[5]=b.y;  mk[6]=b.z;  mk[7]=b.w;
        mk[8]=c.x;  mk[9]=c.y;  mk[10]=c.z; mk[11]=c.w;
        mk[12]=d.x; mk[13]=d.y; mk[14]=d.z; mk[15]=d.w;
    }

    // ---- 2. softmax scalars by wave 0 ----
    if (t < 64) {
        float a = logp[t], b = logp[t + 64];
        float m = fmaxf(a, b);
        #pragma unroll
        for (int o = 32; o > 0; o >>= 1) m = fmaxf(m, __shfl_xor(m, o));
        float ea = expf(a - m), eb = expf(b - m);
        float s = ea + eb;
        #pragma unroll
        for (int o = 32; o > 0; o >>= 1) s += __shfl_xor(s, o);
        if (t == 0) { smx[0] = m; smx[1] = s; }
    }

    // ---- 3. wave-shfl scan selection ----
    int cnt = 0;
    #pragma unroll
    for (int k = 0; k < 16; ++k) cnt += (mk[k] == p) ? 1 : 0;
    int v = cnt;                                   // inclusive wave scan
    #pragma unroll
    for (int o = 1; o < 64; o <<= 1) {
        int u = __shfl_up(v, o);
        if (lane >= o) v += u;
    }
    if (lane == 63) wtot[wid] = v;
    __syncthreads();                               // barrier #1 (cheap)
    int woff = 0;
    #pragma unroll
    for (int w = 0; w < 4; ++w) woff += (w < wid) ? wtot[w] : 0;
    const int base = woff + v - cnt;               // block-wide exclusive
    const int n    = wtot[0] + wtot[1] + wtot[2] + wtot[3];
    const int lo   = (n * q) / BPP;
    const int hi   = (n * (q + 1)) / BPP;
    const int nq   = hi - lo;
    if (nq == 0) return;               // uniform across block, safe

    // ---- 4a. issue sigma -> LDS async, pre-swizzled source (G21/m173) ----
    // final layout: LDS slot (r*32+c) holds sigma row r, col4 c^(r&7)
    {
        const float4* src = reinterpret_cast<const float4*>(sigma)
                            + (size_t)p * 4096;
        #pragma unroll
        for (int w = 0; w < 16; ++w) {
            const int idx = w * 256 + t;           // linear float4 LDS slot
            const int r = idx >> 5, c = idx & 31;
            const float4* gp = src + (r * 32 + (c ^ (r & 7)));
            luint* lp = (luint*)(smat + (w * 256 + wid * 64)); // wave-uniform
            __builtin_amdgcn_global_load_lds((guint*)gp, lp, 16, 0, 0);
        }
    }

    // ---- 4b. rank loop (runs while sigma streams) ----
    const float pw = expf(logp[p] - smx[0]) / smx[1];
    {
        int r = base;
        #pragma unroll
        for (int k = 0; k < 16; ++k) {
            if (mk[k] == p) {
                if (r >= lo && r < hi) slist[r - lo] = t * 16 + k;
                ++r;
            }
        }
    }
    __syncthreads();                               // barrier #2 (drains glds)

    // ---- 5. row i -> 32 float4 regs; per-sample uniform y + fmacs ----
    float4 sr[32];
    #pragma unroll
    for (int u = 0; u < 32; ++u)
        sr[u] = smat[i * 32 + (u ^ (i & 7))];

    const float posv = pos[p * NDIM + i];

    for (int s = hf; s < nq; s += 2) {
        const int sid = __builtin_amdgcn_readfirstlane(slist[s]);
        const float4* y = reinterpret_cast<const float4*>(
            gaussian + (size_t)sid * NDIM);
        float a0 = 0.f, a1 = 0.f, a2 = 0.f, a3 = 0.f;
        #pragma unroll
        for (int u = 0; u < 32; ++u) {
            float4 yv = y[u];                    // wave-uniform -> scalar path
            float4 sv = sr[u];
            a0 += sv.x * yv.x;  a1 += sv.y * yv.y;
            a2 += sv.z * yv.z;  a3 += sv.w * yv.w;
        }
        out[sid * NDIM + i] = posv + ((a0 + a1) + (a2 + a3));
        if (i == 0) {
            wout[sid]   = pw;
            indout[sid] = (float)p;              // exact for 0..127
        }
    }
}

extern "C" void kernel_launch(void* const* d_in, const int* in_sizes, int n_in,
                              void* d_out, int out_size, void* d_ws, size_t ws_size,
                              hipStream_t stream) {
    const float* gaussian = (const float*)d_in[0];   // [4096,128]
    const float* logp     = (const float*)d_in[1];   // [128,1]
    const float* pos      = (const float*)d_in[2];   // [128,128]
    const float* sigma    = (const float*)d_in[3];   // [128,128,128]
    const int*   randind  = (const int*)d_in[4];     // [4096]

    float* out    = (float*)d_out;            // [4096*128]
    float* wout   = out + BATCH * NDIM;       // [4096]
    float* indout = wout + BATCH;             // [4096]

    mix_kernel<<<NBLK, 256, 0, stream>>>(gaussian, logp, pos, sigma, randind,
                                         out, wout, indout);
}

// Round 16
// 15.519 us; speedup vs baseline: 4.6144x; 1.0274x over previous
//
#include <hip/hip_runtime.h>

#define NPART 128
#define NDIM  128
#define BATCH 4096
#define BPP   4                       // blocks per particle
#define NBLK  (NPART * BPP)           // 512 blocks
#define NXCD  8

typedef __attribute__((address_space(1))) const unsigned int guint;
typedef __attribute__((address_space(3))) unsigned int luint;

// ---------------------------------------------------------------------------
// Single fused kernel: 512 blocks x 256 threads. Block = (particle p, qtr q).
// R15 structure with ONE change: sigma LDS swizzle widened from XOR(r&7) to
// XOR(r&31). R15's 8-way spread left sr-fill ds_read_b128 ~8-way bank-
// conflicted (bank group = (u^(i&7))&7 since row stride 512B = 0 mod 128B).
// With (i&31): 64 lanes -> 2 lanes per 4-bank slot = free (m136).
// Same involution applied to glds SOURCE (write) and sr read (G21).
// ---------------------------------------------------------------------------
__global__ __launch_bounds__(256)
void mix_kernel(const float* __restrict__ gaussian,  // [BATCH, NDIM]
                const float* __restrict__ logp,      // [NPART]
                const float* __restrict__ pos,       // [NPART, NDIM]
                const float* __restrict__ sigma,     // [NPART, NDIM, NDIM]
                const int*   __restrict__ randind,   // [BATCH]
                float* __restrict__ out,             // [BATCH, NDIM]
                float* __restrict__ wout,            // [BATCH]
                float* __restrict__ indout) {        // [BATCH]
    const int g  = blockIdx.x;
    // XCD-chunked bijective swizzle (512 % 8 == 0): a particle's 4 sibling
    // blocks land on the same XCD -> sigma_p HBM-fetched once, L2-served 3x.
    const int sg = (g % NXCD) * (NBLK / NXCD) + g / NXCD;
    const int p  = sg >> 2;            // particle
    const int q  = sg & 3;             // quarter of bucket
    const int t  = threadIdx.x;
    const int i  = t & 127;            // output row
    const int hf = t >> 7;             // sample-parity half
    const int lane = t & 63, wid = t >> 6;

    __shared__ float4 smat[NDIM * 32];           // 64 KB swizzled sigma_p
    __shared__ int    wtot[4];
    __shared__ int    slist[160];                // sids of my quarter
    __shared__ float  smx[2];                    // softmax m, S

    // ---- 1. selection loads first: thread t owns samples [16t, 16t+16) ----
    const int4* rnd4 = reinterpret_cast<const int4*>(randind);
    int mk[16];
    {
        int4 a = rnd4[t * 4 + 0], b = rnd4[t * 4 + 1],
             c = rnd4[t * 4 + 2], d = rnd4[t * 4 + 3];
        mk[0]=a.x;  mk[1]=a.y;  mk[2]=a.z;  mk[3]=a.w;
        mk[4]=b.x;  mk[5]=b.y;  mk[6]=b.z;  mk[7]=b.w;
        mk[8]=c.x;  mk[9]=c.y;  mk[10]=c.z; mk[11]=c.w;
        mk[12]=d.x; mk[13]=d.y; mk[14]=d.z; mk[15]=d.w;
    }

    // ---- 2. softmax scalars by wave 0 ----
    if (t < 64) {
        float a = logp[t], b = logp[t + 64];
        float m = fmaxf(a, b);
        #pragma unroll
        for (int o = 32; o > 0; o >>= 1) m = fmaxf(m, __shfl_xor(m, o));
        float ea = expf(a - m), eb = expf(b - m);
        float s = ea + eb;
        #pragma unroll
        for (int o = 32; o > 0; o >>= 1) s += __shfl_xor(s, o);
        if (t == 0) { smx[0] = m; smx[1] = s; }
    }

    // ---- 3. wave-shfl scan selection ----
    int cnt = 0;
    #pragma unroll
    for (int k = 0; k < 16; ++k) cnt += (mk[k] == p) ? 1 : 0;
    int v = cnt;                                   // inclusive wave scan
    #pragma unroll
    for (int o = 1; o < 64; o <<= 1) {
        int u = __shfl_up(v, o);
        if (lane >= o) v += u;
    }
    if (lane == 63) wtot[wid] = v;
    __syncthreads();                               // barrier #1 (cheap)
    int woff = 0;
    #pragma unroll
    for (int w = 0; w < 4; ++w) woff += (w < wid) ? wtot[w] : 0;
    const int base = woff + v - cnt;               // block-wide exclusive
    const int n    = wtot[0] + wtot[1] + wtot[2] + wtot[3];
    const int lo   = (n * q) / BPP;
    const int hi   = (n * (q + 1)) / BPP;
    const int nq   = hi - lo;
    if (nq == 0) return;               // uniform across block, safe

    // ---- 4a. issue sigma -> LDS async, pre-swizzled source (G21/m173) ----
    // final layout: LDS slot (r*32+c) holds sigma row r, col4 c^(r&31)
    {
        const float4* src = reinterpret_cast<const float4*>(sigma)
                            + (size_t)p * 4096;
        #pragma unroll
        for (int w = 0; w < 16; ++w) {
            const int idx = w * 256 + t;           // linear float4 LDS slot
            const int r = idx >> 5, c = idx & 31;
            const float4* gp = src + (r * 32 + (c ^ (r & 31)));
            luint* lp = (luint*)(smat + (w * 256 + wid * 64)); // wave-uniform
            __builtin_amdgcn_global_load_lds((guint*)gp, lp, 16, 0, 0);
        }
    }

    // ---- 4b. rank loop (runs while sigma streams) ----
    const float pw = expf(logp[p] - smx[0]) / smx[1];
    {
        int r = base;
        #pragma unroll
        for (int k = 0; k < 16; ++k) {
            if (mk[k] == p) {
                if (r >= lo && r < hi) slist[r - lo] = t * 16 + k;
                ++r;
            }
        }
    }
    __syncthreads();                               // barrier #2 (drains glds)

    // ---- 5. row i -> 32 float4 regs (2-way-aliased = conflict-free) ----
    float4 sr[32];
    #pragma unroll
    for (int u = 0; u < 32; ++u)
        sr[u] = smat[i * 32 + (u ^ (i & 31))];

    const float posv = pos[p * NDIM + i];

    for (int s = hf; s < nq; s += 2) {
        const int sid = __builtin_amdgcn_readfirstlane(slist[s]);
        const float4* y = reinterpret_cast<const float4*>(
            gaussian + (size_t)sid * NDIM);
        float a0 = 0.f, a1 = 0.f, a2 = 0.f, a3 = 0.f;
        #pragma unroll
        for (int u = 0; u < 32; ++u) {
            float4 yv = y[u];                    // wave-uniform -> scalar path
            float4 sv = sr[u];
            a0 += sv.x * yv.x;  a1 += sv.y * yv.y;
            a2 += sv.z * yv.z;  a3 += sv.w * yv.w;
        }
        out[sid * NDIM + i] = posv + ((a0 + a1) + (a2 + a3));
        if (i == 0) {
            wout[sid]   = pw;
            indout[sid] = (float)p;              // exact for 0..127
        }
    }
}

extern "C" void kernel_launch(void* const* d_in, const int* in_sizes, int n_in,
                              void* d_out, int out_size, void* d_ws, size_t ws_size,
                              hipStream_t stream) {
    const float* gaussian = (const float*)d_in[0];   // [4096,128]
    const float* logp     = (const float*)d_in[1];   // [128,1]
    const float* pos      = (const float*)d_in[2];   // [128,128]
    const float* sigma    = (const float*)d_in[3];   // [128,128,128]
    const int*   randind  = (const int*)d_in[4];     // [4096]

    float* out    = (float*)d_out;            // [4096*128]
    float* wout   = out + BATCH * NDIM;       // [4096]
    float* indout = wout + BATCH;             // [4096]

    mix_kernel<<<NBLK, 256, 0, stream>>>(gaussian, logp, pos, sigma, randind,
                                         out, wout, indout);
}